// Round 4
// baseline (117.118 us; speedup 1.0000x reference)
//
#include <hip/hip_runtime.h>

// NormalizePixelPts: out[f][d] = in[f][d] * scale(d), scale in {1, 1/1280, 1/720}.
// Flat float4 view: n4 = 17,113,088 = 2089 (phase period, prime) x 8192 (reps).
// Each thread owns ONE phase p (scale quad computed once into REGISTERS),
// then streams reps: i = r*2089 + p. Inner loop = load/mul/store only.
// Consecutive lanes -> consecutive float4s: fully coalesced 1KB/wave segments.

#define FEAT_DIM 4178
#define SPLIT    570
#define KBLK     285
#define HALF     2089        // float4-phase period (prime)
#define REPS_TOTAL 8192      // n4 / HALF
#define REPS_PER_BLOCK 32    // 8192 / gridDim.y(256)

typedef float f4 __attribute__((ext_vector_type(4)));  // native vec: OK for nontemporal builtins

__device__ __forceinline__ float scale_for(int d) {
    const float inv_w = 1.0f / 1280.0f;
    const float inv_h = 1.0f / 720.0f;
    if (d >= FEAT_DIM) d -= FEAT_DIM;   // callers pass d < 2*FEAT_DIM
    if (d < SPLIT) {
        int r = d % KBLK;
        if (r == 0 || r == 81 || r >= 164) return 1.0f;
        if (r <= 80) return ((r - 1) & 1) ? inv_h : inv_w;
        return ((r - 82) & 1) ? inv_h : inv_w;  // 82..163 incl. RH-LH pair
    }
    return ((d - 570) & 1) ? inv_h : inv_w;
}

__global__ void __launch_bounds__(256)
normalize_pixel_pts_kernel(const f4* __restrict__ in, f4* __restrict__ out) {
    int p = blockIdx.x * 256 + threadIdx.x;   // phase in [0, 2089)
    if (p >= HALF) return;

    // Per-thread scale quad, computed ONCE (off the hot path).
    int d0 = 4 * p;                       // <= 8352 < 2*FEAT_DIM
    if (d0 >= FEAT_DIM) d0 -= FEAT_DIM;   // even, <= 4176
    f4 s;
    s.x = scale_for(d0);
    s.y = scale_for(d0 + 1);
    s.z = scale_for(d0 + 2);              // may wrap (handled in scale_for)
    s.w = scale_for(d0 + 3);

    int i = blockIdx.y * (REPS_PER_BLOCK * HALF) + p;
    #pragma unroll 4
    for (int r = 0; r < REPS_PER_BLOCK; ++r, i += HALF) {
        f4 v = __builtin_nontemporal_load(&in[i]);
        v *= s;
        __builtin_nontemporal_store(v, &out[i]);
    }
}

extern "C" void kernel_launch(void* const* d_in, const int* in_sizes, int n_in,
                              void* d_out, int out_size, void* d_ws, size_t ws_size,
                              hipStream_t stream) {
    const f4* in = (const f4*)d_in[0];
    f4* out = (f4*)d_out;
    // out_size = 68,452,352 = 4 * 2089 * 8192 exactly.

    dim3 grid((HALF + 255) / 256,            // 9 phase tiles (last ragged: 41)
              REPS_TOTAL / REPS_PER_BLOCK);  // 256 rep chunks
    normalize_pixel_pts_kernel<<<grid, dim3(256, 1, 1), 0, stream>>>(in, out);
}

// Round 5
// 112.195 us; speedup vs baseline: 1.0439x; 1.0439x over previous
//
#include <hip/hip_runtime.h>

// NormalizePixelPts: out[f][d] = in[f][d] * scale(d), scale in {1, 1/1280, 1/720}.
// Flat float4 view: n4 = 17,113,088; float4-phase period = 2089 (prime).
// Trick: launch exactly 2089 blocks x 256 threads = 534,784 threads and
// grid-stride by 534,784 = 256*2089 ≡ 0 (mod 2089): each thread's phase is
// INVARIANT, so its scale quad lives in registers (computed once), while the
// sweep stays dense/coalesced (each grid-iteration = one contiguous 8.5 MB span).
// n4 / 534,784 = 32 iterations exactly — no tail.

#define FEAT_DIM 4178
#define SPLIT    570
#define KBLK     285
#define HALF     2089                 // float4-phase period (prime)
#define TOTAL_THREADS (HALF * 256)    // 534,784
#define ITERS    32                   // n4 / TOTAL_THREADS

typedef float f4 __attribute__((ext_vector_type(4)));

__device__ __forceinline__ float scale_for(int d) {
    const float inv_w = 1.0f / 1280.0f;
    const float inv_h = 1.0f / 720.0f;
    if (d >= FEAT_DIM) d -= FEAT_DIM;   // callers pass d < 2*FEAT_DIM
    if (d < SPLIT) {
        int r = d % KBLK;
        if (r == 0 || r == 81 || r >= 164) return 1.0f;
        if (r <= 80) return ((r - 1) & 1) ? inv_h : inv_w;
        return ((r - 82) & 1) ? inv_h : inv_w;  // 82..163 incl. RH-LH pair
    }
    return ((d - 570) & 1) ? inv_h : inv_w;
}

__global__ void __launch_bounds__(256)
normalize_pixel_pts_kernel(const f4* __restrict__ in, f4* __restrict__ out) {
    int tid = blockIdx.x * 256 + threadIdx.x;   // 0 .. 534,783
    int p = tid % HALF;                          // phase, invariant under +=TOTAL_THREADS

    // Per-thread scale quad, computed ONCE (off the hot path).
    int d0 = 4 * p;                        // <= 8352 < 2*FEAT_DIM
    if (d0 >= FEAT_DIM) d0 -= FEAT_DIM;    // even, <= 4176
    f4 s;
    s.x = scale_for(d0);
    s.y = scale_for(d0 + 1);
    s.z = scale_for(d0 + 2);               // may wrap (handled in scale_for)
    s.w = scale_for(d0 + 3);

    int i = tid;                           // max index 17,113,087 < 2^31
    #pragma unroll 4
    for (int r = 0; r < ITERS; ++r, i += TOTAL_THREADS) {
        f4 v = in[i];
        v *= s;
        out[i] = v;
    }
}

extern "C" void kernel_launch(void* const* d_in, const int* in_sizes, int n_in,
                              void* d_out, int out_size, void* d_ws, size_t ws_size,
                              hipStream_t stream) {
    const f4* in = (const f4*)d_in[0];
    f4* out = (f4*)d_out;
    // out_size = 68,452,352 = 4 * 2089 * 256 * 32 exactly.
    normalize_pixel_pts_kernel<<<HALF, 256, 0, stream>>>(in, out);
}